// Round 23
// baseline (209.008 us; speedup 1.0000x reference)
//
#include <hip/hip_runtime.h>
#include <hip/hip_bf16.h>
#include <stdint.h>

typedef __bf16 bf16x8 __attribute__((ext_vector_type(8)));
typedef float f32x4 __attribute__((ext_vector_type(4)));
typedef float f32x16 __attribute__((ext_vector_type(16)));
typedef unsigned int u32x4 __attribute__((ext_vector_type(4)));

static constexpr int Bn = 8, Sn = 4096, En = 128;

__device__ __forceinline__ unsigned short f2bf(float f) {
  unsigned u = __builtin_bit_cast(unsigned, f);
  u += 0x7fffu + ((u >> 16) & 1u);
  return (unsigned short)(u >> 16);
}

__device__ __forceinline__ float bf2f(unsigned short s) {
  return __builtin_bit_cast(float, (unsigned)s << 16);
}

__device__ __forceinline__ unsigned cvtpk(float a, float b) {
  unsigned r;
  asm("v_cvt_pk_bf16_f32 %0, %1, %2" : "=v"(r) : "v"(a), "v"(b));
  return r;
}

// v_permlane32_swap_b32 vdst, vsrc: vdst.hi <-> vsrc.lo.
__device__ __forceinline__ void plswap(unsigned &a, unsigned &b) {
  asm("v_permlane32_swap_b32 %0, %1" : "+v"(a), "+v"(b));
}

// ---------------- Kernel 0: one-time W -> bf16 conversion ----------------
__global__ __launch_bounds__(256) void wconv_kernel(
    const float* __restrict__ Wq, const float* __restrict__ Wk,
    const float* __restrict__ Wv, unsigned short* __restrict__ wb)
{
  const int f4 = blockIdx.x * 256 + threadIdx.x;   // 0..12287 (3 x 4096 float4)
  const int mat = f4 >> 12, off = f4 & 4095;
  const float* src = (mat == 0) ? Wq : (mat == 1) ? Wk : Wv;
  const float4 v = *(const float4*)&src[off * 4];
  ushort4 pk;
  pk.x = f2bf(v.x); pk.y = f2bf(v.y); pk.z = f2bf(v.z); pk.w = f2bf(v.w);
  *(ushort4*)&wb[(size_t)mat * 16384 + off * 4] = pk;
}

// ---------------- Kernel 1: fused QKV projection + bias + PReLU ----------------
__global__ __launch_bounds__(512) void qkv_kernel(
    const float* __restrict__ x, const unsigned short* __restrict__ wb,
    const float* __restrict__ bq, const float* __restrict__ aq,
    const float* __restrict__ bk, const float* __restrict__ ak,
    const float* __restrict__ bv, const float* __restrict__ av,
    unsigned short* __restrict__ qo, unsigned short* __restrict__ kf,
    unsigned short* __restrict__ vf)
{
  __shared__ __align__(16) unsigned short xs[128 * 136];
  __shared__ __align__(16) unsigned short wsh[128 * 136];
  const int tid = threadIdx.x;
  const int r0 = blockIdx.x * 128;

  for (int i = 0; i < 8; ++i) {
    int cid = tid + i * 512;
    int row = cid >> 5, c4 = cid & 31;
    const float4 v = *(const float4*)&x[(size_t)(r0 + row) * 128 + c4 * 4];
    unsigned short* d = &xs[row * 136 + c4 * 4];
    d[0] = f2bf(v.x); d[1] = f2bf(v.y); d[2] = f2bf(v.z); d[3] = f2bf(v.w);
  }

  const int lane = tid & 63, wid = tid >> 6;   // wid 0..7
  const int g = lane >> 4, ln = lane & 15;
  const float* Bs[3] = {bq, bk, bv};
  const float* As[3] = {aq, ak, av};
  bf16x8 afrag[4];

  for (int mat = 0; mat < 3; ++mat) {
    __syncthreads();
    for (int i = 0; i < 4; ++i) {
      int cid = tid + i * 512;
      int row = cid >> 4, c8 = cid & 15;
      *(uint4*)&wsh[row * 136 + c8 * 8] =
          *(const uint4*)&wb[(size_t)mat * 16384 + row * 128 + c8 * 8];
    }
    __syncthreads();

    if (mat == 0) {
      for (int ks = 0; ks < 4; ++ks)
        afrag[ks] = *(const bf16x8*)&xs[(wid * 16 + ln) * 136 + ks * 32 + g * 8];
    }
    const float alpha = As[mat][0];
    f32x4 acc[8];
    for (int nt = 0; nt < 8; ++nt) acc[nt] = (f32x4)(0.f);
    for (int nt = 0; nt < 8; ++nt)
      for (int ks = 0; ks < 4; ++ks) {
        bf16x8 bfrag = *(const bf16x8*)&wsh[(nt * 16 + ln) * 136 + ks * 32 + g * 8];
        acc[nt] = __builtin_amdgcn_mfma_f32_16x16x32_bf16(afrag[ks], bfrag, acc[nt], 0, 0, 0);
      }
    const int mbase = r0 + wid * 16 + g * 4;
    for (int nt = 0; nt < 8; ++nt) {
      const int n = nt * 16 + ln;
      const float bias = Bs[mat][n];
      float vv[4];
      for (int r = 0; r < 4; ++r) {
        float t = acc[nt][r] + bias;
        vv[r] = t >= 0.f ? t : alpha * t;
      }
      if (mat == 0) {
        for (int r = 0; r < 4; ++r) qo[(size_t)(mbase + r) * 128 + n] = f2bf(vv[r]);
      } else if (mat == 1) {
        for (int r = 0; r < 4; ++r) {
          const int key = mbase + r, bb = key >> 12, sl = key & 4095;
          const size_t addr = ((size_t)bb << 20) + (size_t)(sl >> 5) * 8192
                            + nt * 1024 + ((ln >> 3) & 1) * 512
                            + (sl & 31) * 16 + ((ln & 7) << 1);
          *(unsigned short*)((char*)kf + addr) = f2bf(vv[r]);
        }
      } else {
        const int bb = mbase >> 12, sl = mbase & 4095;
        const int kb64 = sl >> 6, kk = sl & 63;
        const int ks2 = kk >> 4, hi2 = (kk >> 3) & 1, j0 = kk & 7;
        const size_t addr = ((size_t)bb << 20) + (size_t)kb64 * 16384
                          + (n >> 5) * 4096 + ks2 * 1024 + hi2 * 512
                          + (n & 31) * 16 + (j0 << 1);
        ushort4 pk;
        pk.x = f2bf(vv[0]); pk.y = f2bf(vv[1]); pk.z = f2bf(vv[2]); pk.w = f2bf(vv[3]);
        *(ushort4*)((char*)vf + addr) = pk;
      }
    }
  }
}

// ---------------- shared staging helpers (fragment-major) ----------------
__device__ __forceinline__ void load_frag(const char* kfb, const char* vfb, int kt,
                                          int tid, uint4* kr, uint4* vr) {
  const char* ks = kfb + (size_t)kt * 16384;
  const char* vs = vfb + (size_t)kt * 16384;
  kr[0] = *(const uint4*)(ks + tid * 16);
  kr[1] = *(const uint4*)(ks + 8192 + tid * 16);
  vr[0] = *(const uint4*)(vs + tid * 16);
  vr[1] = *(const uint4*)(vs + 8192 + tid * 16);
}

__device__ __forceinline__ void store_frag(char* slot, int tid,
                                           const uint4* kr, const uint4* vr) {
  *(uint4*)(slot + tid * 16) = kr[0];
  *(uint4*)(slot + 8192 + tid * 16) = kr[1];
  *(uint4*)(slot + 16384 + tid * 16) = vr[0];
  *(uint4*)(slot + 24576 + tid * 16) = vr[1];
}

// ---------------- Kernel 2a: R21 attn (fallback, split<=2): FROZEN ----------------
template <int KSPLIT>
__global__ __launch_bounds__(512, 2) void attn_kernel(
    const unsigned short* __restrict__ q,
    const unsigned short* __restrict__ kf,
    const unsigned short* __restrict__ vf,
    unsigned short* __restrict__ opart, float* __restrict__ mpart,
    float* __restrict__ lpart, float* __restrict__ out)
{
  __shared__ __align__(16) char smem[98304];
  const int tid = threadIdx.x;
  const int lane = tid & 63, wid = tid >> 6;
  const int NS = 8 * KSPLIT;
  const int bid = blockIdx.x;
  const int s_ = bid % NS;
  const int qt = bid / NS;
  const int b  = s_ / KSPLIT;
  const int kh = s_ % KSPLIT;
  const int hi = lane >> 5, ln = lane & 31;
  const size_t bOff = (size_t)b * Sn * En;

  const int nkt = (Sn / KSPLIT) / 64;
  const int kbase = kh * (Sn / KSPLIT);
  const char* kfb = (const char*)kf + ((size_t)b << 20) + (size_t)(kbase >> 5) * 8192;
  const char* vfb = (const char*)vf + ((size_t)b << 20) + (size_t)(kbase >> 6) * 16384;

  const int qrow = qt * 256 + wid * 32 + ln;
  bf16x8 qf[8];
  #pragma unroll
  for (int s = 0; s < 8; ++s)
    qf[s] = *(const bf16x8*)((const char*)(q + bOff) + (size_t)qrow * 256 + s * 32 + hi * 16);

  f32x16 acc[4];
  #pragma unroll
  for (int et = 0; et < 4; ++et) acc[et] = (f32x16)(0.f);
  float m_run = -1e30f, lsum = 0.f;

  const float cst = 1.4426950408889634f * 0.08838834764831845f;

  auto qk = [&](const char* slot, f32x16& st0, f32x16& st1) {
    const char* kp = slot + hi * 512 + ln * 16;
    st0 = (f32x16)(0.f); st1 = (f32x16)(0.f);
    __builtin_amdgcn_s_setprio(1);
    #pragma unroll
    for (int s = 0; s < 8; ++s) {
      bf16x8 kf0 = *(const bf16x8*)(kp + s * 1024);
      bf16x8 kf1 = *(const bf16x8*)(kp + 8192 + s * 1024);
      st0 = __builtin_amdgcn_mfma_f32_32x32x16_bf16(kf0, qf[s], st0, 0, 0, 0);
      st1 = __builtin_amdgcn_mfma_f32_32x32x16_bf16(kf1, qf[s], st1, 0, 0, 0);
    }
    __builtin_amdgcn_s_setprio(0);
  };

  auto sm_pv = [&](const char* slot, const f32x16& st0, const f32x16& st1) {
    const char* vp = slot + 16384 + hi * 512 + ln * 16;
    float t16[16];
    #pragma unroll
    for (int i = 0; i < 16; ++i) t16[i] = fmaxf(st0[i], st1[i]);
    float t8[8];
    #pragma unroll
    for (int i = 0; i < 8; ++i) t8[i] = fmaxf(t16[i], t16[i + 8]);
    float t4[4];
    #pragma unroll
    for (int i = 0; i < 4; ++i) t4[i] = fmaxf(t8[i], t8[i + 4]);
    float vtile = fmaxf(fmaxf(t4[0], t4[1]), fmaxf(t4[2], t4[3])) * cst;
    vtile = fmaxf(vtile, __shfl_xor(vtile, 32));

    if (__any(vtile > m_run + 8.0f)) {
      float mnew = fmaxf(m_run, vtile);
      float al = __builtin_amdgcn_exp2f(m_run - mnew);
      #pragma unroll
      for (int et = 0; et < 4; ++et) acc[et] *= al;
      lsum *= al;
      m_run = mnew;
    }

    float p[32];
    #pragma unroll
    for (int i = 0; i < 16; ++i) p[i]      = __builtin_amdgcn_exp2f(fmaf(st0[i], cst, -m_run));
    #pragma unroll
    for (int i = 0; i < 16; ++i) p[16 + i] = __builtin_amdgcn_exp2f(fmaf(st1[i], cst, -m_run));

    float s16[16];
    #pragma unroll
    for (int i = 0; i < 16; ++i) s16[i] = p[i] + p[16 + i];
    float s8[8];
    #pragma unroll
    for (int i = 0; i < 8; ++i) s8[i] = s16[i] + s16[i + 8];
    float s4[4];
    #pragma unroll
    for (int i = 0; i < 4; ++i) s4[i] = s8[i] + s8[i + 4];
    float tsum = (s4[0] + s4[1]) + (s4[2] + s4[3]);
    tsum += __shfl_xor(tsum, 32);
    lsum += tsum;

    unsigned wa[8], wb2[8];
    #pragma unroll
    for (int g2 = 0; g2 < 8; ++g2) {
      wa[g2]  = cvtpk(p[4 * g2], p[4 * g2 + 1]);
      wb2[g2] = cvtpk(p[4 * g2 + 2], p[4 * g2 + 3]);
    }
    bf16x8 pb[4];
    #pragma unroll
    for (int ks = 0; ks < 4; ++ks) {
      unsigned w0 = wa[2 * ks], w2 = wa[2 * ks + 1];
      plswap(w0, w2);
      unsigned w1 = wb2[2 * ks], w3 = wb2[2 * ks + 1];
      plswap(w1, w3);
      u32x4 w = {w0, w1, w2, w3};
      pb[ks] = __builtin_bit_cast(bf16x8, w);
    }

    __builtin_amdgcn_s_setprio(1);
    #pragma unroll
    for (int ks = 0; ks < 4; ++ks) {
      #pragma unroll
      for (int et = 0; et < 4; ++et) {
        bf16x8 vfr = *(const bf16x8*)(vp + et * 4096 + ks * 1024);
        acc[et] = __builtin_amdgcn_mfma_f32_32x32x16_bf16(vfr, pb[ks], acc[et], 0, 0, 0);
      }
    }
    __builtin_amdgcn_s_setprio(0);
  };

  char* s0 = smem;
  char* s1 = smem + 32768;
  char* s2 = smem + 65536;

  uint4 kregA[2], vregA[2], kregB[2], vregB[2];
  load_frag(kfb, vfb, 0, tid, kregA, vregA);
  store_frag(s0, tid, kregA, vregA);
  load_frag(kfb, vfb, 1, tid, kregB, vregB);
  store_frag(s1, tid, kregB, vregB);
  if (nkt > 2) load_frag(kfb, vfb, 2, tid, kregA, vregA);
  __syncthreads();
  f32x16 sA0, sA1, sB0, sB1;
  qk(s0, sA0, sA1);

  for (int t = 0; t < nkt; t += 2) {
    if (t + 2 < nkt) store_frag(s2, tid, kregA, vregA);
    if (t + 3 < nkt) load_frag(kfb, vfb, t + 3, tid, kregB, vregB);
    qk(s1, sB0, sB1);
    sm_pv(s0, sA0, sA1);
    __syncthreads();

    if (t + 3 < nkt) store_frag(s0, tid, kregB, vregB);
    if (t + 4 < nkt) load_frag(kfb, vfb, t + 4, tid, kregA, vregA);
    if (t + 2 < nkt) qk(s2, sA0, sA1);
    sm_pv(s1, sB0, sB1);
    __syncthreads();

    char* tt = s0; s0 = s2; s2 = s1; s1 = tt;
  }

  if (KSPLIT > 1 && lane < 32) {
    const size_t idx = (size_t)kh * (Bn * Sn) + (size_t)b * Sn + qt * 256 + wid * 32 + ln;
    mpart[idx] = m_run;
    lpart[idx] = lsum;
  }

  __syncthreads();
  const float inv = (KSPLIT == 1) ? (1.0f / lsum) : 1.0f;
  char* sl = smem + wid * 8192;
  char* outb;
  if (KSPLIT == 1)
    outb = (char*)(out + ((size_t)b * Sn + qt * 256 + wid * 32) * En);
  else
    outb = (char*)(opart + ((size_t)kh * (Bn * Sn) + (size_t)b * Sn + qt * 256 + wid * 32) * En);

  #pragma unroll
  for (int h = 0; h < 2; ++h) {
    #pragma unroll
    for (int e2 = 0; e2 < 2; ++e2) {
      const int et = 2 * h + e2;
      #pragma unroll
      for (int rg = 0; rg < 4; ++rg) {
        f32x4 v;
        #pragma unroll
        for (int j = 0; j < 4; ++j) v[j] = acc[et][rg * 4 + j] * inv;
        const int addr = ln * 256 + e2 * 128 + rg * 32 + hi * 16;
        *(f32x4*)(sl + (addr ^ ((ln & 7) << 4))) = v;
      }
    }
    asm volatile("s_waitcnt lgkmcnt(0)" ::: "memory");
    __builtin_amdgcn_sched_barrier(0);
    #pragma unroll
    for (int i = 0; i < 8; ++i) {
      const int flat = i * 1024 + lane * 16;
      const int qr = flat >> 8, col = flat & 255;
      f32x4 v = *(const f32x4*)(sl + ((qr * 256 + col) ^ ((qr & 7) << 4)));
      if (KSPLIT == 1) {
        *(f32x4*)(outb + (size_t)qr * 512 + h * 256 + col) = v;
      } else {
        ushort4 pk;
        pk.x = f2bf(v[0]); pk.y = f2bf(v[1]); pk.z = f2bf(v[2]); pk.w = f2bf(v[3]);
        *(ushort4*)(outb + (size_t)qr * 256 + h * 128 + (col >> 1)) = pk;
      }
    }
    if (h == 0) {
      asm volatile("s_waitcnt lgkmcnt(0)" ::: "memory");
      __builtin_amdgcn_sched_barrier(0);
    }
  }
}

// ---------------- Kernel 2b: ticketed attn, KSPLIT=4, batch-per-XCD ----------------
// Runtime XCD-aware ticketing (R22-verified machinery) with CORRECTED decode:
// XCD x owns exactly batch x (all 4 kh quarters, all 16 qt) -> per-XCD L2 working
// set = Q 1MB + K/V 2MB = 3MB <= 4MB. Partials stored non-temporally so the
// ~4MB of output write-allocate cannot evict it.
__global__ __launch_bounds__(512, 4) void attn4_kernel(
    const unsigned short* __restrict__ q,
    const unsigned short* __restrict__ kf,
    const unsigned short* __restrict__ vf,
    unsigned short* __restrict__ opart, float* __restrict__ mpart,
    float* __restrict__ lpart, unsigned* __restrict__ tickets)
{
  __shared__ __align__(16) char smem[65536];   // 2 slots x 32K; epilogue reuses
  __shared__ int tk_sh;
  const int tid = threadIdx.x;
  const int lane = tid & 63, wid = tid >> 6;
  const int hi = lane >> 5, ln = lane & 31;

  if (tid == 0) {
    unsigned xcc;
    asm volatile("s_getreg_b32 %0, hwreg(HW_REG_XCC_ID)" : "=s"(xcc));
    xcc &= 7u;
    int t = -1;
    for (int i = 0; i < 8; ++i) {
      unsigned qx2 = (xcc + (unsigned)i) & 7u;
      unsigned old = atomicAdd(&tickets[qx2], 1u);
      if (old < 64u) { t = (int)(qx2 * 64u + old); break; }
    }
    tk_sh = t;
  }
  __syncthreads();
  const int tk = tk_sh;
  const int qx = tk >> 6, idx = tk & 63;
  const int b  = qx;                           // batch == XCD  (the fix)
  const int kh = idx & 3;                      // KSPLIT=4 quarter
  const int qt = idx >> 2;                     // 0..15

  const size_t bOff = (size_t)b * Sn * En;
  const int nkt = 16;                          // 4096/4/64
  const int kbase = kh * 1024;
  const char* kfb = (const char*)kf + ((size_t)b << 20) + (size_t)(kbase >> 5) * 8192;
  const char* vfb = (const char*)vf + ((size_t)b << 20) + (size_t)(kbase >> 6) * 16384;

  const int qrow = qt * 256 + wid * 32 + ln;
  bf16x8 qf[8];
  #pragma unroll
  for (int s = 0; s < 8; ++s)
    qf[s] = *(const bf16x8*)((const char*)(q + bOff) + (size_t)qrow * 256 + s * 32 + hi * 16);

  f32x16 acc[4];
  #pragma unroll
  for (int et = 0; et < 4; ++et) acc[et] = (f32x16)(0.f);
  float m_run = -1e30f, lsum = 0.f;
  const float cst = 1.4426950408889634f * 0.08838834764831845f;

  char* const s0 = smem;
  char* const s1 = smem + 32768;

  uint4 kreg[2], vreg[2];
  load_frag(kfb, vfb, 0, tid, kreg, vreg);
  store_frag(s0, tid, kreg, vreg);
  load_frag(kfb, vfb, 1, tid, kreg, vreg);
  __syncthreads();                 // publish tile 0

  for (int kt = 0; kt < nkt; ++kt) {
    const char* cur = (kt & 1) ? s1 : s0;
    const char* kp = cur + hi * 512 + ln * 16;
    const char* vp = cur + 16384 + hi * 512 + ln * 16;

    f32x16 st0 = (f32x16)(0.f), st1 = (f32x16)(0.f);
    __builtin_amdgcn_s_setprio(1);
    #pragma unroll
    for (int s = 0; s < 8; ++s) {
      bf16x8 kf0 = *(const bf16x8*)(kp + s * 1024);
      bf16x8 kf1 = *(const bf16x8*)(kp + 8192 + s * 1024);
      st0 = __builtin_amdgcn_mfma_f32_32x32x16_bf16(kf0, qf[s], st0, 0, 0, 0);
      st1 = __builtin_amdgcn_mfma_f32_32x32x16_bf16(kf1, qf[s], st1, 0, 0, 0);
    }
    __builtin_amdgcn_s_setprio(0);

    float t16[16];
    #pragma unroll
    for (int i = 0; i < 16; ++i) t16[i] = fmaxf(st0[i], st1[i]);
    float t8[8];
    #pragma unroll
    for (int i = 0; i < 8; ++i) t8[i] = fmaxf(t16[i], t16[i + 8]);
    float t4[4];
    #pragma unroll
    for (int i = 0; i < 4; ++i) t4[i] = fmaxf(t8[i], t8[i + 4]);
    float vtile = fmaxf(fmaxf(t4[0], t4[1]), fmaxf(t4[2], t4[3])) * cst;
    vtile = fmaxf(vtile, __shfl_xor(vtile, 32));

    if (__any(vtile > m_run + 8.0f)) {
      float mnew = fmaxf(m_run, vtile);
      float al = __builtin_amdgcn_exp2f(m_run - mnew);
      #pragma unroll
      for (int et = 0; et < 4; ++et) acc[et] *= al;
      lsum *= al;
      m_run = mnew;
    }

    float p[32];
    #pragma unroll
    for (int i = 0; i < 16; ++i) p[i]      = __builtin_amdgcn_exp2f(fmaf(st0[i], cst, -m_run));
    #pragma unroll
    for (int i = 0; i < 16; ++i) p[16 + i] = __builtin_amdgcn_exp2f(fmaf(st1[i], cst, -m_run));

    float s16[16];
    #pragma unroll
    for (int i = 0; i < 16; ++i) s16[i] = p[i] + p[16 + i];
    float s8[8];
    #pragma unroll
    for (int i = 0; i < 8; ++i) s8[i] = s16[i] + s16[i + 8];
    float s4[4];
    #pragma unroll
    for (int i = 0; i < 4; ++i) s4[i] = s8[i] + s8[i + 4];
    float tsum = (s4[0] + s4[1]) + (s4[2] + s4[3]);
    tsum += __shfl_xor(tsum, 32);
    lsum += tsum;

    unsigned wa[8], wb2[8];
    #pragma unroll
    for (int g2 = 0; g2 < 8; ++g2) {
      wa[g2]  = cvtpk(p[4 * g2], p[4 * g2 + 1]);
      wb2[g2] = cvtpk(p[4 * g2 + 2], p[4 * g2 + 3]);
    }
    bf16x8 pb[4];
    #pragma unroll
    for (int ks = 0; ks < 4; ++ks) {
      unsigned w0 = wa[2 * ks], w2 = wa[2 * ks + 1];
      plswap(w0, w2);
      unsigned w1 = wb2[2 * ks], w3 = wb2[2 * ks + 1];
      plswap(w1, w3);
      u32x4 w = {w0, w1, w2, w3};
      pb[ks] = __builtin_bit_cast(bf16x8, w);
    }

    __builtin_amdgcn_s_setprio(1);
    #pragma unroll
    for (int ks = 0; ks < 4; ++ks) {
      #pragma unroll
      for (int et = 0; et < 4; ++et) {
        bf16x8 vfr = *(const bf16x8*)(vp + et * 4096 + ks * 1024);
        acc[et] = __builtin_amdgcn_mfma_f32_32x32x16_bf16(vfr, pb[ks], acc[et], 0, 0, 0);
      }
    }
    __builtin_amdgcn_s_setprio(0);

    __syncthreads();               // all reads of the other slot (next store dst) done
    if (kt + 1 < nkt) store_frag((kt & 1) ? s0 : s1, tid, kreg, vreg);
    __syncthreads();               // publish tile kt+1
    if (kt + 2 < nkt) load_frag(kfb, vfb, kt + 2, tid, kreg, vreg);
  }

  if (lane < 32) {
    const size_t idx2 = (size_t)kh * (Bn * Sn) + (size_t)b * Sn + qt * 256 + wid * 32 + ln;
    __builtin_nontemporal_store(m_run, &mpart[idx2]);
    __builtin_nontemporal_store(lsum, &lpart[idx2]);
  }

  // epilogue: per-wave 8 KB region, bf16 partials stored non-temporally
  __syncthreads();
  char* sl = smem + wid * 8192;
  char* outb = (char*)(opart + ((size_t)kh * (Bn * Sn) + (size_t)b * Sn + qt * 256 + wid * 32) * En);

  #pragma unroll
  for (int h = 0; h < 2; ++h) {
    #pragma unroll
    for (int e2 = 0; e2 < 2; ++e2) {
      const int et = 2 * h + e2;
      #pragma unroll
      for (int rg = 0; rg < 4; ++rg) {
        f32x4 v;
        #pragma unroll
        for (int j = 0; j < 4; ++j) v[j] = acc[et][rg * 4 + j];
        const int addr = ln * 256 + e2 * 128 + rg * 32 + hi * 16;
        *(f32x4*)(sl + (addr ^ ((ln & 7) << 4))) = v;
      }
    }
    asm volatile("s_waitcnt lgkmcnt(0)" ::: "memory");
    __builtin_amdgcn_sched_barrier(0);
    #pragma unroll
    for (int i = 0; i < 8; ++i) {
      const int flat = i * 1024 + lane * 16;
      const int qr = flat >> 8, col = flat & 255;
      f32x4 v = *(const f32x4*)(sl + ((qr * 256 + col) ^ ((qr & 7) << 4)));
      const unsigned lo = cvtpk(v[0], v[1]), hi2 = cvtpk(v[2], v[3]);
      const unsigned long long uv = (unsigned long long)lo
                                  | ((unsigned long long)hi2 << 32);
      __builtin_nontemporal_store(
          uv, (unsigned long long*)(outb + (size_t)qr * 256 + h * 128 + (col >> 1)));
    }
    if (h == 0) {
      asm volatile("s_waitcnt lgkmcnt(0)" ::: "memory");
      __builtin_amdgcn_sched_barrier(0);
    }
  }
}

// ---------------- Kernel 3: merge NSPLIT K-partials (bf16 partials) ----------------
template <int NSPLIT>
__global__ __launch_bounds__(256) void combine_kernel(
    const unsigned short* __restrict__ op, const float* __restrict__ mp,
    const float* __restrict__ lp, float* __restrict__ out)
{
  const int idx = blockIdx.x * 256 + threadIdx.x;
  const int row = idx >> 5;
  const int BS = Bn * Sn;
  float m = -1e30f;
  #pragma unroll
  for (int j = 0; j < NSPLIT; ++j) m = fmaxf(m, mp[j * BS + row]);
  float den = 0.f;
  f32x4 sum = (f32x4)(0.f);
  #pragma unroll
  for (int j = 0; j < NSPLIT; ++j) {
    const float w = __builtin_amdgcn_exp2f(mp[j * BS + row] - m);
    den += w * lp[j * BS + row];
    ushort4 u = *(const ushort4*)(op + (size_t)j * ((size_t)BS * En) + (size_t)idx * 4);
    f32x4 o;
    o[0] = bf2f(u.x); o[1] = bf2f(u.y); o[2] = bf2f(u.z); o[3] = bf2f(u.w);
    sum += o * w;
  }
  const float inv = 1.f / den;
  ((f32x4*)out)[idx] = sum * inv;
}

extern "C" void kernel_launch(void* const* d_in, const int* in_sizes, int n_in,
                              void* d_out, int out_size, void* d_ws, size_t ws_size,
                              hipStream_t stream) {
  const float* x  = (const float*)d_in[0];
  const float* Wq = (const float*)d_in[1];
  const float* bq = (const float*)d_in[2];
  const float* aq = (const float*)d_in[3];
  const float* Wk = (const float*)d_in[4];
  const float* bk = (const float*)d_in[5];
  const float* ak = (const float*)d_in[6];
  const float* Wv = (const float*)d_in[7];
  const float* bv = (const float*)d_in[8];
  const float* av = (const float*)d_in[9];

  const size_t BSE = (size_t)Bn * Sn * En;          // 4,194,304
  const size_t BS  = (size_t)Bn * Sn;
  char* base = (char*)d_ws;
  unsigned short* qws = (unsigned short*)base;
  unsigned short* kws = qws + BSE;                  // K fragment-major (8 MB)
  unsigned short* vws = kws + BSE;                  // V fragment-major (8 MB)
  const size_t fixed = 3 * BSE * 2;                 // 24 MB
  unsigned short* opart = (unsigned short*)(base + fixed);

  auto need = [&](int j) {
    return fixed + (size_t)j * BSE * 2 + (size_t)j * BS * 8 + 98304 + 256;
  };
  int split = 1;
  if (ws_size >= need(4)) split = 4;
  else if (ws_size >= need(2)) split = 2;

  float* mpart = (float*)(base + fixed + (size_t)split * BSE * 2);
  float* lpart = mpart + (size_t)split * BS;
  unsigned short* wb = (unsigned short*)(lpart + (size_t)split * BS);  // 96 KB
  unsigned* tickets = (unsigned*)((char*)wb + 98304);                  // 32 B

  wconv_kernel<<<48, 256, 0, stream>>>(Wq, Wk, Wv, wb);
  qkv_kernel<<<256, 512, 0, stream>>>(x, wb, bq, aq, bk, ak, bv, av,
                                      qws, kws, vws);
  if (split == 4) {
    hipMemsetAsync(tickets, 0, 32, stream);
    attn4_kernel<<<512, 512, 0, stream>>>(qws, kws, vws, opart, mpart, lpart,
                                          tickets);
    combine_kernel<4><<<4096, 256, 0, stream>>>(opart, mpart, lpart, (float*)d_out);
  } else if (split == 2) {
    attn_kernel<2><<<256, 512, 0, stream>>>(qws, kws, vws, opart, mpart, lpart,
                                            (float*)d_out);
    combine_kernel<2><<<4096, 256, 0, stream>>>(opart, mpart, lpart, (float*)d_out);
  } else {
    attn_kernel<1><<<128, 512, 0, stream>>>(qws, kws, vws, opart, mpart, lpart,
                                            (float*)d_out);
  }
}

// Round 24
// 134.763 us; speedup vs baseline: 1.5509x; 1.5509x over previous
//
#include <hip/hip_runtime.h>
#include <hip/hip_bf16.h>
#include <stdint.h>

typedef __bf16 bf16x8 __attribute__((ext_vector_type(8)));
typedef float f32x4 __attribute__((ext_vector_type(4)));
typedef float f32x16 __attribute__((ext_vector_type(16)));
typedef unsigned int u32x4 __attribute__((ext_vector_type(4)));

static constexpr int Bn = 8, Sn = 4096, En = 128;

__device__ __forceinline__ unsigned short f2bf(float f) {
  unsigned u = __builtin_bit_cast(unsigned, f);
  u += 0x7fffu + ((u >> 16) & 1u);
  return (unsigned short)(u >> 16);
}

__device__ __forceinline__ float bf2f(unsigned short s) {
  return __builtin_bit_cast(float, (unsigned)s << 16);
}

__device__ __forceinline__ unsigned cvtpk(float a, float b) {
  unsigned r;
  asm("v_cvt_pk_bf16_f32 %0, %1, %2" : "=v"(r) : "v"(a), "v"(b));
  return r;
}

// v_permlane32_swap_b32 vdst, vsrc: vdst.hi <-> vsrc.lo.
__device__ __forceinline__ void plswap(unsigned &a, unsigned &b) {
  asm("v_permlane32_swap_b32 %0, %1" : "+v"(a), "+v"(b));
}

// ---------------- Kernel 0: one-time W -> bf16 conversion ----------------
__global__ __launch_bounds__(256) void wconv_kernel(
    const float* __restrict__ Wq, const float* __restrict__ Wk,
    const float* __restrict__ Wv, unsigned short* __restrict__ wb)
{
  const int f4 = blockIdx.x * 256 + threadIdx.x;   // 0..12287 (3 x 4096 float4)
  const int mat = f4 >> 12, off = f4 & 4095;
  const float* src = (mat == 0) ? Wq : (mat == 1) ? Wk : Wv;
  const float4 v = *(const float4*)&src[off * 4];
  ushort4 pk;
  pk.x = f2bf(v.x); pk.y = f2bf(v.y); pk.z = f2bf(v.z); pk.w = f2bf(v.w);
  *(ushort4*)&wb[(size_t)mat * 16384 + off * 4] = pk;
}

// ---------------- Kernel 1: fused QKV projection + bias + PReLU ----------------
// 512-thread blocks, 128-row x tiles; W staged as pre-converted bf16 (pure copy).
// Q row-major bf16 [B][S][128];
// K fragment-major (R11-verified): KF[b][key_blk32][s:8][hi:2][lane:32][8 bf16]
// V fragment-major (R11-verified): VF[b][key_blk64][et:4][ks:4][hi:2][lane:32][8 bf16]
__global__ __launch_bounds__(512) void qkv_kernel(
    const float* __restrict__ x, const unsigned short* __restrict__ wb,
    const float* __restrict__ bq, const float* __restrict__ aq,
    const float* __restrict__ bk, const float* __restrict__ ak,
    const float* __restrict__ bv, const float* __restrict__ av,
    unsigned short* __restrict__ qo, unsigned short* __restrict__ kf,
    unsigned short* __restrict__ vf)
{
  __shared__ __align__(16) unsigned short xs[128 * 136];
  __shared__ __align__(16) unsigned short wsh[128 * 136];
  const int tid = threadIdx.x;
  const int r0 = blockIdx.x * 128;

  // stage x tile (fp32 -> bf16): 128 rows x 32 float4 chunks = 4096; 8 iters
  for (int i = 0; i < 8; ++i) {
    int cid = tid + i * 512;
    int row = cid >> 5, c4 = cid & 31;
    const float4 v = *(const float4*)&x[(size_t)(r0 + row) * 128 + c4 * 4];
    unsigned short* d = &xs[row * 136 + c4 * 4];
    d[0] = f2bf(v.x); d[1] = f2bf(v.y); d[2] = f2bf(v.z); d[3] = f2bf(v.w);
  }

  const int lane = tid & 63, wid = tid >> 6;   // wid 0..7
  const int g = lane >> 4, ln = lane & 15;
  const float* Bs[3] = {bq, bk, bv};
  const float* As[3] = {aq, ak, av};
  bf16x8 afrag[4];

  for (int mat = 0; mat < 3; ++mat) {
    __syncthreads();
    // stage W (bf16 copy): 16384 ushorts = 2048 x ushort8; 4 iters
    for (int i = 0; i < 4; ++i) {
      int cid = tid + i * 512;
      int row = cid >> 4, c8 = cid & 15;
      *(uint4*)&wsh[row * 136 + c8 * 8] =
          *(const uint4*)&wb[(size_t)mat * 16384 + row * 128 + c8 * 8];
    }
    __syncthreads();

    if (mat == 0) {
      for (int ks = 0; ks < 4; ++ks)
        afrag[ks] = *(const bf16x8*)&xs[(wid * 16 + ln) * 136 + ks * 32 + g * 8];
    }
    const float alpha = As[mat][0];
    f32x4 acc[8];
    for (int nt = 0; nt < 8; ++nt) acc[nt] = (f32x4)(0.f);
    for (int nt = 0; nt < 8; ++nt)
      for (int ks = 0; ks < 4; ++ks) {
        bf16x8 bfrag = *(const bf16x8*)&wsh[(nt * 16 + ln) * 136 + ks * 32 + g * 8];
        acc[nt] = __builtin_amdgcn_mfma_f32_16x16x32_bf16(afrag[ks], bfrag, acc[nt], 0, 0, 0);
      }
    const int mbase = r0 + wid * 16 + g * 4;
    for (int nt = 0; nt < 8; ++nt) {
      const int n = nt * 16 + ln;
      const float bias = Bs[mat][n];
      float vv[4];
      for (int r = 0; r < 4; ++r) {
        float t = acc[nt][r] + bias;
        vv[r] = t >= 0.f ? t : alpha * t;
      }
      if (mat == 0) {
        for (int r = 0; r < 4; ++r) qo[(size_t)(mbase + r) * 128 + n] = f2bf(vv[r]);
      } else if (mat == 1) {
        // K fragment-major (R11): e=n -> s=nt, hi=(ln>>3)&1, j=ln&7; key=mbase+r.
        for (int r = 0; r < 4; ++r) {
          const int key = mbase + r, bb = key >> 12, sl = key & 4095;
          const size_t addr = ((size_t)bb << 20) + (size_t)(sl >> 5) * 8192
                            + nt * 1024 + ((ln >> 3) & 1) * 512
                            + (sl & 31) * 16 + ((ln & 7) << 1);
          *(unsigned short*)((char*)kf + addr) = f2bf(vv[r]);
        }
      } else {
        // V fragment-major (R11): e=n -> et=n>>5, lane=n&31; keys mbase.. -> j0..
        const int bb = mbase >> 12, sl = mbase & 4095;
        const int kb64 = sl >> 6, kk = sl & 63;
        const int ks2 = kk >> 4, hi2 = (kk >> 3) & 1, j0 = kk & 7;  // j0 in {0,4}
        const size_t addr = ((size_t)bb << 20) + (size_t)kb64 * 16384
                          + (n >> 5) * 4096 + ks2 * 1024 + hi2 * 512
                          + (n & 31) * 16 + (j0 << 1);
        ushort4 pk;
        pk.x = f2bf(vv[0]); pk.y = f2bf(vv[1]); pk.z = f2bf(vv[2]); pk.w = f2bf(vv[3]);
        *(ushort4*)((char*)vf + addr) = pk;
      }
    }
  }
}

// ---------------- Kernel 2: flash attention, swapped-QK 32x32, O^T accum ----------------
// R18 structure (best: 113 us attn): 3-slot rolling pipeline, 1 barrier/tile,
// fragment-major K+V LDS (linear lane access, conflict-free), T15 qk||softmax
// interleave, bf16 partials.  FROZEN from R20/R21.
__device__ __forceinline__ void load_frag(const char* kfb, const char* vfb, int kt,
                                          int tid, uint4* kr, uint4* vr) {
  const char* ks = kfb + (size_t)kt * 16384;
  const char* vs = vfb + (size_t)kt * 16384;
  kr[0] = *(const uint4*)(ks + tid * 16);
  kr[1] = *(const uint4*)(ks + 8192 + tid * 16);
  vr[0] = *(const uint4*)(vs + tid * 16);
  vr[1] = *(const uint4*)(vs + 8192 + tid * 16);
}

__device__ __forceinline__ void store_frag(char* slot, int tid,
                                           const uint4* kr, const uint4* vr) {
  *(uint4*)(slot + tid * 16) = kr[0];
  *(uint4*)(slot + 8192 + tid * 16) = kr[1];
  *(uint4*)(slot + 16384 + tid * 16) = vr[0];
  *(uint4*)(slot + 24576 + tid * 16) = vr[1];
}

template <int KSPLIT>
__global__ __launch_bounds__(512, 2) void attn_kernel(
    const unsigned short* __restrict__ q,
    const unsigned short* __restrict__ kf,
    const unsigned short* __restrict__ vf,
    unsigned short* __restrict__ opart, float* __restrict__ mpart,
    float* __restrict__ lpart, float* __restrict__ out)
{
  __shared__ __align__(16) char smem[98304];  // 3 slots x (16K K + 16K V); epilogue reuses
  const int tid = threadIdx.x;
  const int lane = tid & 63, wid = tid >> 6;   // wid 0..7
  // XCD-locked decode: stream s = (b,kh); all 16 qt-blocks of s land on XCD s%8.
  const int NS = 8 * KSPLIT;
  const int bid = blockIdx.x;
  const int s_ = bid % NS;
  const int qt = bid / NS;
  const int b  = s_ / KSPLIT;
  const int kh = s_ % KSPLIT;
  const int hi = lane >> 5, ln = lane & 31;
  const size_t bOff = (size_t)b * Sn * En;

  const int nkt = (Sn / KSPLIT) / 64;          // even
  const int kbase = kh * (Sn / KSPLIT);
  const char* kfb = (const char*)kf + ((size_t)b << 20) + (size_t)(kbase >> 5) * 8192;
  const char* vfb = (const char*)vf + ((size_t)b << 20) + (size_t)(kbase >> 6) * 16384;

  // Q fragments (B-operand of swapped QK): col=q=ln, k-elems e=16s+8hi+j
  const int qrow = qt * 256 + wid * 32 + ln;
  bf16x8 qf[8];
  #pragma unroll
  for (int s = 0; s < 8; ++s)
    qf[s] = *(const bf16x8*)((const char*)(q + bOff) + (size_t)qrow * 256 + s * 32 + hi * 16);

  f32x16 acc[4];   // O^T accum: acc[et], col=q=ln, row e = 32*et + (reg&3)+8*(reg>>2)+4*hi
  #pragma unroll
  for (int et = 0; et < 4; ++et) acc[et] = (f32x16)(0.f);
  float m_run = -1e30f, lsum = 0.f;

  const float cst = 1.4426950408889634f * 0.08838834764831845f;  // log2(e)/sqrt(128)

  // ---- QK^T (swapped): S^T = K * Q; fragment-major LDS, linear reads ----
  auto qk = [&](const char* slot, f32x16& st0, f32x16& st1) {
    const char* kp = slot + hi * 512 + ln * 16;
    st0 = (f32x16)(0.f); st1 = (f32x16)(0.f);
    __builtin_amdgcn_s_setprio(1);
    #pragma unroll
    for (int s = 0; s < 8; ++s) {
      bf16x8 kf0 = *(const bf16x8*)(kp + s * 1024);
      bf16x8 kf1 = *(const bf16x8*)(kp + 8192 + s * 1024);
      st0 = __builtin_amdgcn_mfma_f32_32x32x16_bf16(kf0, qf[s], st0, 0, 0, 0);
      st1 = __builtin_amdgcn_mfma_f32_32x32x16_bf16(kf1, qf[s], st1, 0, 0, 0);
    }
    __builtin_amdgcn_s_setprio(0);
  };

  // ---- online softmax + pack + PV for one tile (V fragment-major in slot) ----
  auto sm_pv = [&](const char* slot, const f32x16& st0, const f32x16& st1) {
    const char* vp = slot + 16384 + hi * 512 + ln * 16;
    float t16[16];
    #pragma unroll
    for (int i = 0; i < 16; ++i) t16[i] = fmaxf(st0[i], st1[i]);
    float t8[8];
    #pragma unroll
    for (int i = 0; i < 8; ++i) t8[i] = fmaxf(t16[i], t16[i + 8]);
    float t4[4];
    #pragma unroll
    for (int i = 0; i < 4; ++i) t4[i] = fmaxf(t8[i], t8[i + 4]);
    float vtile = fmaxf(fmaxf(t4[0], t4[1]), fmaxf(t4[2], t4[3])) * cst;
    vtile = fmaxf(vtile, __shfl_xor(vtile, 32));

    if (__any(vtile > m_run + 8.0f)) {      // defer-max: rescale only on real growth
      float mnew = fmaxf(m_run, vtile);
      float al = __builtin_amdgcn_exp2f(m_run - mnew);
      #pragma unroll
      for (int et = 0; et < 4; ++et) acc[et] *= al;
      lsum *= al;
      m_run = mnew;
    }

    float p[32];
    #pragma unroll
    for (int i = 0; i < 16; ++i) p[i]      = __builtin_amdgcn_exp2f(fmaf(st0[i], cst, -m_run));
    #pragma unroll
    for (int i = 0; i < 16; ++i) p[16 + i] = __builtin_amdgcn_exp2f(fmaf(st1[i], cst, -m_run));

    float s16[16];
    #pragma unroll
    for (int i = 0; i < 16; ++i) s16[i] = p[i] + p[16 + i];
    float s8[8];
    #pragma unroll
    for (int i = 0; i < 8; ++i) s8[i] = s16[i] + s16[i + 8];
    float s4[4];
    #pragma unroll
    for (int i = 0; i < 4; ++i) s4[i] = s8[i] + s8[i + 4];
    float tsum = (s4[0] + s4[1]) + (s4[2] + s4[3]);
    tsum += __shfl_xor(tsum, 32);
    lsum += tsum;

    unsigned wa[8], wb2[8];
    #pragma unroll
    for (int g2 = 0; g2 < 8; ++g2) {
      wa[g2]  = cvtpk(p[4 * g2], p[4 * g2 + 1]);
      wb2[g2] = cvtpk(p[4 * g2 + 2], p[4 * g2 + 3]);
    }
    bf16x8 pb[4];
    #pragma unroll
    for (int ks = 0; ks < 4; ++ks) {
      unsigned w0 = wa[2 * ks], w2 = wa[2 * ks + 1];
      plswap(w0, w2);
      unsigned w1 = wb2[2 * ks], w3 = wb2[2 * ks + 1];
      plswap(w1, w3);
      u32x4 w = {w0, w1, w2, w3};
      pb[ks] = __builtin_bit_cast(bf16x8, w);
    }

    __builtin_amdgcn_s_setprio(1);
    #pragma unroll
    for (int ks = 0; ks < 4; ++ks) {
      #pragma unroll
      for (int et = 0; et < 4; ++et) {
        bf16x8 vfr = *(const bf16x8*)(vp + et * 4096 + ks * 1024);
        acc[et] = __builtin_amdgcn_mfma_f32_32x32x16_bf16(vfr, pb[ks], acc[et], 0, 0, 0);
      }
    }
    __builtin_amdgcn_s_setprio(0);
  };

  char* s0 = smem;
  char* s1 = smem + 32768;
  char* s2 = smem + 65536;

  uint4 kregA[2], vregA[2], kregB[2], vregB[2];
  // prologue: stage tiles 0,1 into s0,s1; prefetch tile 2 into regsA; qk(0)
  load_frag(kfb, vfb, 0, tid, kregA, vregA);
  store_frag(s0, tid, kregA, vregA);
  load_frag(kfb, vfb, 1, tid, kregB, vregB);
  store_frag(s1, tid, kregB, vregB);
  if (nkt > 2) load_frag(kfb, vfb, 2, tid, kregA, vregA);
  __syncthreads();                 // publish tiles 0,1
  f32x16 sA0, sA1, sB0, sB1;
  qk(s0, sA0, sA1);                // S(0)

  // invariant at loop top: s0=t (sA=S(t)), s1=t+1 (published), s2 free,
  //                        regsA = tile t+2 (if any)
  for (int t = 0; t < nkt; t += 2) {
    // --- half 1 (tile t): stage t+2 -> s2 (disjoint from reads of s0,s1) ---
    if (t + 2 < nkt) store_frag(s2, tid, kregA, vregA);
    if (t + 3 < nkt) load_frag(kfb, vfb, t + 3, tid, kregB, vregB);
    qk(s1, sB0, sB1);              // S(t+1); softmax below overlaps MFMA latency
    sm_pv(s0, sA0, sA1);           // tile t
    __syncthreads();               // publish t+2; all reads of s0 done -> s0 free

    // --- half 2 (tile t+1): stage t+3 -> s0 ---
    if (t + 3 < nkt) store_frag(s0, tid, kregB, vregB);
    if (t + 4 < nkt) load_frag(kfb, vfb, t + 4, tid, kregA, vregA);
    if (t + 2 < nkt) qk(s2, sA0, sA1);   // S(t+2)
    sm_pv(s1, sB0, sB1);           // tile t+1
    __syncthreads();               // publish t+3; all reads of s1 done -> s1 free

    // rotate: new (s0,s1,s2) = (t+2, t+3, free) = (s2, s0, s1)
    char* tt = s0; s0 = s2; s2 = s1; s1 = tt;
  }

  // ---- stash m,l for combine ----
  if (KSPLIT > 1 && lane < 32) {
    const size_t idx = (size_t)kh * (Bn * Sn) + (size_t)b * Sn + qt * 256 + wid * 32 + ln;
    mpart[idx] = m_run;
    lpart[idx] = lsum;
  }

  // ---- epilogue: per-wave-EXCLUSIVE 8 KB region, two 64-col half transposes ----
  __syncthreads();
  const float inv = (KSPLIT == 1) ? (1.0f / lsum) : 1.0f;
  char* sl = smem + wid * 8192;
  char* outb;
  if (KSPLIT == 1)
    outb = (char*)(out + ((size_t)b * Sn + qt * 256 + wid * 32) * En);
  else
    outb = (char*)(opart + ((size_t)kh * (Bn * Sn) + (size_t)b * Sn + qt * 256 + wid * 32) * En);

  #pragma unroll
  for (int h = 0; h < 2; ++h) {
    #pragma unroll
    for (int e2 = 0; e2 < 2; ++e2) {
      const int et = 2 * h + e2;
      #pragma unroll
      for (int rg = 0; rg < 4; ++rg) {
        f32x4 v;
        #pragma unroll
        for (int j = 0; j < 4; ++j) v[j] = acc[et][rg * 4 + j] * inv;
        const int addr = ln * 256 + e2 * 128 + rg * 32 + hi * 16;
        *(f32x4*)(sl + (addr ^ ((ln & 7) << 4))) = v;
      }
    }
    asm volatile("s_waitcnt lgkmcnt(0)" ::: "memory");
    __builtin_amdgcn_sched_barrier(0);
    #pragma unroll
    for (int i = 0; i < 8; ++i) {
      const int flat = i * 1024 + lane * 16;
      const int qr = flat >> 8, col = flat & 255;
      f32x4 v = *(const f32x4*)(sl + ((qr * 256 + col) ^ ((qr & 7) << 4)));
      if (KSPLIT == 1) {
        *(f32x4*)(outb + (size_t)qr * 512 + h * 256 + col) = v;
      } else {
        ushort4 pk;
        pk.x = f2bf(v[0]); pk.y = f2bf(v[1]); pk.z = f2bf(v[2]); pk.w = f2bf(v[3]);
        *(ushort4*)(outb + (size_t)qr * 256 + h * 128 + (col >> 1)) = pk;
      }
    }
    if (h == 0) {
      asm volatile("s_waitcnt lgkmcnt(0)" ::: "memory");
      __builtin_amdgcn_sched_barrier(0);
    }
  }
}

// ---------------- Kernel 3: merge NSPLIT K-partials (bf16 partials) ----------------
template <int NSPLIT>
__global__ __launch_bounds__(256) void combine_kernel(
    const unsigned short* __restrict__ op, const float* __restrict__ mp,
    const float* __restrict__ lp, float* __restrict__ out)
{
  const int idx = blockIdx.x * 256 + threadIdx.x;   // f32x4 index
  const int row = idx >> 5;
  const int BS = Bn * Sn;
  float m = -1e30f;
  #pragma unroll
  for (int j = 0; j < NSPLIT; ++j) m = fmaxf(m, mp[j * BS + row]);
  float den = 0.f;
  f32x4 sum = (f32x4)(0.f);
  #pragma unroll
  for (int j = 0; j < NSPLIT; ++j) {
    const float w = __builtin_amdgcn_exp2f(mp[j * BS + row] - m);
    den += w * lp[j * BS + row];
    ushort4 u = *(const ushort4*)(op + (size_t)j * ((size_t)BS * En) + (size_t)idx * 4);
    f32x4 o;
    o[0] = bf2f(u.x); o[1] = bf2f(u.y); o[2] = bf2f(u.z); o[3] = bf2f(u.w);
    sum += o * w;
  }
  const float inv = 1.f / den;
  ((f32x4*)out)[idx] = sum * inv;
}

extern "C" void kernel_launch(void* const* d_in, const int* in_sizes, int n_in,
                              void* d_out, int out_size, void* d_ws, size_t ws_size,
                              hipStream_t stream) {
  const float* x  = (const float*)d_in[0];
  const float* Wq = (const float*)d_in[1];
  const float* bq = (const float*)d_in[2];
  const float* aq = (const float*)d_in[3];
  const float* Wk = (const float*)d_in[4];
  const float* bk = (const float*)d_in[5];
  const float* ak = (const float*)d_in[6];
  const float* Wv = (const float*)d_in[7];
  const float* bv = (const float*)d_in[8];
  const float* av = (const float*)d_in[9];

  const size_t BSE = (size_t)Bn * Sn * En;          // 4,194,304
  const size_t BS  = (size_t)Bn * Sn;
  char* base = (char*)d_ws;
  unsigned short* qws = (unsigned short*)base;
  unsigned short* kws = qws + BSE;                  // K fragment-major buffer (8 MB)
  unsigned short* vws = kws + BSE;                  // V fragment-major buffer (8 MB)
  const size_t fixed = 3 * BSE * 2;                 // 24 MB of bf16 Q/KF/VF
  unsigned short* opart = (unsigned short*)(base + fixed);

  auto need = [&](int j) {
    return fixed + (size_t)j * BSE * 2 + (size_t)j * BS * 8 + 98304;
  };
  int split = 1;
  if (ws_size >= need(2)) split = 2;

  float* mpart = (float*)(base + fixed + (size_t)split * BSE * 2);
  float* lpart = mpart + (size_t)split * BS;
  unsigned short* wb = (unsigned short*)(lpart + (size_t)split * BS);  // 96 KB

  wconv_kernel<<<48, 256, 0, stream>>>(Wq, Wk, Wv, wb);
  qkv_kernel<<<256, 512, 0, stream>>>(x, wb, bq, aq, bk, ak, bv, av,
                                      qws, kws, vws);
  if (split == 2) {
    attn_kernel<2><<<256, 512, 0, stream>>>(qws, kws, vws, opart, mpart, lpart,
                                            (float*)d_out);
    combine_kernel<2><<<4096, 256, 0, stream>>>(opart, mpart, lpart, (float*)d_out);
  } else {
    attn_kernel<1><<<128, 512, 0, stream>>>(qws, kws, vws, opart, mpart, lpart,
                                            (float*)d_out);
  }
}